// Round 1
// baseline (861.600 us; speedup 1.0000x reference)
//
#include <hip/hip_runtime.h>
#include <hip/hip_bf16.h>

#define B_ 256
#define N_ 256
#define C_ 512
#define H_ 16
#define HD_ 32
#define SCALE_ 0.17677669529663687f

typedef __attribute__((ext_vector_type(8))) short short8;
typedef __attribute__((ext_vector_type(4))) float f32x4v;

static __device__ __forceinline__ unsigned short f2bf(float f) {
  union { float f; unsigned u; } x; x.f = f;
  unsigned r = x.u + 0x7fffu + ((x.u >> 16) & 1u);
  return (unsigned short)(r >> 16);
}

// K0: tm[b][j] = temb[b,:]@temb_w[:,j] + temb_b[j] + qkv_b[j]   [B,1536] f32
__global__ void temb_mod_kernel(const float* __restrict__ temb,
                                const float* __restrict__ temb_w,
                                const float* __restrict__ temb_b,
                                const float* __restrict__ qkv_b,
                                float* __restrict__ tm) {
  __shared__ float ts[512];
  const int b = blockIdx.x, t = threadIdx.x;
  ts[t] = temb[b * 512 + t];
  ts[t + 256] = temb[b * 512 + 256 + t];
  __syncthreads();
  float acc[6];
#pragma unroll
  for (int u = 0; u < 6; ++u) acc[u] = temb_b[t + u * 256] + qkv_b[t + u * 256];
  for (int k = 0; k < 512; ++k) {
    float tv = ts[k];
#pragma unroll
    for (int u = 0; u < 6; ++u) acc[u] += tv * temb_w[(size_t)k * 1536 + t + u * 256];
  }
#pragma unroll
  for (int u = 0; u < 6; ++u) tm[(size_t)b * 1536 + t + u * 256] = acc[u];
}

// K1: fused qkv-GEMM + windowed attention per (b,h). 512 threads = 8 waves,
// wave w owns 32 query rows. Writes attn_out bf16 [B*N, C].
__global__ __launch_bounds__(512)
void fused_attn_kernel(const float* __restrict__ x,
                       const float* __restrict__ qkv_w,
                       const float* __restrict__ rpb,
                       const float* __restrict__ tm,
                       unsigned short* __restrict__ attn_out) {
  // LDS: strides padded to 40 bf16 (80B) -> conflict-free b128 frag reads
  __shared__ short xs[256 * 40];    // x tile  [row][k32]
  __shared__ short wTs[96 * 40];    // W^T     [col96][k32]
  __shared__ short qs[256 * 40];    // q       [n][hd32] (scale folded in)
  __shared__ short ks[256 * 40];    // k       [n][hd32]
  __shared__ short vTs[32 * 264];   // v^T     [hd][n256]
  __shared__ short pbuf[256 * 40];  // P tiles [n][k32] (per-wave slices)
  __shared__ float biasT[961];      // rpb column h

  const int bh = blockIdx.x;
  const int b = bh >> 4, h = bh & 15;
  const int tid = threadIdx.x;
  const int w = tid >> 6;
  const int l = tid & 63;
  const int l16 = l & 15, g = l >> 4;

  for (int e = tid; e < 961; e += 512) biasT[e] = rpb[e * 16 + h];

  const float* xb = x + (size_t)b * (N_ * C_);
  f32x4v acc[2][6];
#pragma unroll
  for (int mt = 0; mt < 2; ++mt)
#pragma unroll
    for (int nt = 0; nt < 6; ++nt) acc[mt][nt] = (f32x4v)(0.0f);

  // ---- Phase A: qkv = x[b] @ qkv_w[:, 96 cols of head h] ----
  for (int k0 = 0; k0 < 512; k0 += 32) {
#pragma unroll
    for (int i = 0; i < 4; ++i) {          // stage x: 256x32 f32 -> bf16
      int f = tid + i * 512;
      int row = f >> 3, c4 = (f & 7) << 2;
      float4 v = *reinterpret_cast<const float4*>(xb + (size_t)row * 512 + k0 + c4);
      *reinterpret_cast<ushort4*>(&xs[row * 40 + c4]) =
          make_ushort4(f2bf(v.x), f2bf(v.y), f2bf(v.z), f2bf(v.w));
    }
#pragma unroll
    for (int i = 0; i < 6; ++i) {          // stage W^T: 96x32
      int f = tid + i * 512;
      int kk = f / 96, c = f - kk * 96;
      int gcol = ((c >> 5) << 9) + (h << 5) + (c & 31);  // q/k/v chunk select
      wTs[c * 40 + kk] = (short)f2bf(qkv_w[(size_t)(k0 + kk) * 1536 + gcol]);
    }
    __syncthreads();
    short8 af[2], bfr[6];
#pragma unroll
    for (int mt = 0; mt < 2; ++mt)
      af[mt] = *reinterpret_cast<short8*>(&xs[(w * 32 + mt * 16 + l16) * 40 + g * 8]);
#pragma unroll
    for (int nt = 0; nt < 6; ++nt)
      bfr[nt] = *reinterpret_cast<short8*>(&wTs[(nt * 16 + l16) * 40 + g * 8]);
#pragma unroll
    for (int mt = 0; mt < 2; ++mt)
#pragma unroll
      for (int nt = 0; nt < 6; ++nt)
        acc[mt][nt] = __builtin_amdgcn_mfma_f32_16x16x32_bf16(af[mt], bfr[nt], acc[mt][nt], 0, 0, 0);
    __syncthreads();
  }

  // ---- epilogue A: +temb_mod bias, scale q, scatter to qs/ks/vTs ----
  const float* tmb = tm + (size_t)b * 1536;
#pragma unroll
  for (int mt = 0; mt < 2; ++mt) {
#pragma unroll
    for (int nt = 0; nt < 6; ++nt) {
      int c96 = nt * 16 + l16;
      int part = c96 >> 5, d = c96 & 31;   // 0=q 1=k 2=v
      float tmv = tmb[(part << 9) + (h << 5) + d];
#pragma unroll
      for (int j = 0; j < 4; ++j) {
        int row = w * 32 + mt * 16 + g * 4 + j;   // D-layout: row=(l>>4)*4+j
        float val = acc[mt][nt][j] + tmv;
        if (part == 0) qs[row * 40 + d] = (short)f2bf(val * SCALE_);
        else if (part == 1) ks[row * 40 + d] = (short)f2bf(val);
        else vTs[d * 264 + row] = (short)f2bf(val);
      }
    }
  }
  __syncthreads();

  // ---- pass 1: online per-lane max/sum over score tiles ----
  short8 aq[2];
#pragma unroll
  for (int mt = 0; mt < 2; ++mt)
    aq[mt] = *reinterpret_cast<short8*>(&qs[(w * 32 + mt * 16 + l16) * 40 + g * 8]);

  float m[2][4], lr[2][4];
#pragma unroll
  for (int mt = 0; mt < 2; ++mt)
#pragma unroll
    for (int j = 0; j < 4; ++j) { m[mt][j] = -3.0e38f; lr[mt][j] = 0.0f; }

  for (int kt = 0; kt < 16; ++kt) {
    short8 bk = *reinterpret_cast<short8*>(&ks[(kt * 16 + l16) * 40 + g * 8]);
    int col = kt * 16 + l16;
    int yj = col >> 4, xj = col & 15;
#pragma unroll
    for (int mt = 0; mt < 2; ++mt) {
      f32x4v s4 = __builtin_amdgcn_mfma_f32_16x16x32_bf16(aq[mt], bk, (f32x4v)(0.0f), 0, 0, 0);
#pragma unroll
      for (int j = 0; j < 4; ++j) {
        int row = w * 32 + mt * 16 + g * 4 + j;
        float s = s4[j] + biasT[((row >> 4) - yj + 15) * 31 + ((row & 15) - xj + 15)];
        float mo = m[mt][j];
        float mn = fmaxf(mo, s);
        lr[mt][j] = lr[mt][j] * __expf(mo - mn) + __expf(s - mn);
        m[mt][j] = mn;
      }
    }
  }
  // merge (m,l) across the 16 lanes holding one row's columns
#pragma unroll
  for (int mt = 0; mt < 2; ++mt)
#pragma unroll
    for (int j = 0; j < 4; ++j) {
      float mm = m[mt][j], ll = lr[mt][j];
#pragma unroll
      for (int off = 1; off < 16; off <<= 1) {
        float mo = __shfl_xor(mm, off);
        float lo = __shfl_xor(ll, off);
        float mn = fmaxf(mm, mo);
        ll = ll * __expf(mm - mn) + lo * __expf(mo - mn);
        mm = mn;
      }
      m[mt][j] = mm;
      lr[mt][j] = 1.0f / ll;
    }

  // ---- pass 2: recompute S, P = exp(S-m)/l -> pbuf, PV MFMA ----
  f32x4v oacc[2][2];
#pragma unroll
  for (int mt = 0; mt < 2; ++mt)
#pragma unroll
    for (int nt = 0; nt < 2; ++nt) oacc[mt][nt] = (f32x4v)(0.0f);

  for (int kp = 0; kp < 8; ++kp) {
#pragma unroll
    for (int half = 0; half < 2; ++half) {
      int kt = kp * 2 + half;
      short8 bk = *reinterpret_cast<short8*>(&ks[(kt * 16 + l16) * 40 + g * 8]);
      int col = kt * 16 + l16;
      int yj = col >> 4, xj = col & 15;
#pragma unroll
      for (int mt = 0; mt < 2; ++mt) {
        f32x4v s4 = __builtin_amdgcn_mfma_f32_16x16x32_bf16(aq[mt], bk, (f32x4v)(0.0f), 0, 0, 0);
#pragma unroll
        for (int j = 0; j < 4; ++j) {
          int row = w * 32 + mt * 16 + g * 4 + j;
          float s = s4[j] + biasT[((row >> 4) - yj + 15) * 31 + ((row & 15) - xj + 15)];
          float p = __expf(s - m[mt][j]) * lr[mt][j];
          pbuf[(size_t)row * 40 + half * 16 + l16] = (short)f2bf(p);
        }
      }
    }
    __syncthreads();
#pragma unroll
    for (int mt = 0; mt < 2; ++mt) {
      short8 ap = *reinterpret_cast<short8*>(&pbuf[(w * 32 + mt * 16 + l16) * 40 + g * 8]);
#pragma unroll
      for (int nt = 0; nt < 2; ++nt) {
        short8 bv = *reinterpret_cast<short8*>(&vTs[(nt * 16 + l16) * 264 + kp * 32 + g * 8]);
        oacc[mt][nt] = __builtin_amdgcn_mfma_f32_16x16x32_bf16(ap, bv, oacc[mt][nt], 0, 0, 0);
      }
    }
    __syncthreads();
  }

  // ---- write attn_out bf16 [b*N+n][h*32+d] ----
  unsigned short* ao = attn_out + ((size_t)b * N_) * C_ + h * HD_;
#pragma unroll
  for (int mt = 0; mt < 2; ++mt)
#pragma unroll
    for (int nt = 0; nt < 2; ++nt)
#pragma unroll
      for (int j = 0; j < 4; ++j) {
        int row = w * 32 + mt * 16 + g * 4 + j;
        ao[(size_t)row * C_ + nt * 16 + l16] = f2bf(oacc[mt][nt][j]);
      }
}

// K2: out = attn_out @ proj_w + proj_b   (65536x512 @ 512x512, bf16 MFMA)
__global__ __launch_bounds__(256)
void proj_kernel(const unsigned short* __restrict__ attn,
                 const float* __restrict__ proj_w,
                 const float* __restrict__ proj_b,
                 float* __restrict__ out) {
  __shared__ short as_[128 * 40];
  __shared__ short bt[128 * 40];
  const int tid = threadIdx.x;
  const int w = tid >> 6, l = tid & 63, l16 = l & 15, g = l >> 4;
  const int m0 = (blockIdx.x >> 2) << 7;
  const int c0 = (blockIdx.x & 3) << 7;
  const int wr = w >> 1, wc = w & 1;
  f32x4v acc[4][4];
#pragma unroll
  for (int mt = 0; mt < 4; ++mt)
#pragma unroll
    for (int nt = 0; nt < 4; ++nt) acc[mt][nt] = (f32x4v)(0.0f);

  for (int k0 = 0; k0 < 512; k0 += 32) {
#pragma unroll
    for (int i = 0; i < 2; ++i) {            // A tile 128x32 (already bf16)
      int f = tid + i * 256;
      int row = f >> 2, c8 = (f & 3) << 3;
      *reinterpret_cast<short8*>(&as_[row * 40 + c8]) =
          *reinterpret_cast<const short8*>(attn + (size_t)(m0 + row) * 512 + k0 + c8);
    }
#pragma unroll
    for (int i = 0; i < 4; ++i) {            // B^T tile 128x32 (f32 -> bf16)
      int f4 = tid + i * 256;
      int kk = f4 >> 5, c = (f4 & 31) << 2;
      float4 v = *reinterpret_cast<const float4*>(proj_w + (size_t)(k0 + kk) * 512 + c0 + c);
      bt[(c + 0) * 40 + kk] = (short)f2bf(v.x);
      bt[(c + 1) * 40 + kk] = (short)f2bf(v.y);
      bt[(c + 2) * 40 + kk] = (short)f2bf(v.z);
      bt[(c + 3) * 40 + kk] = (short)f2bf(v.w);
    }
    __syncthreads();
    short8 af[4], bfr[4];
#pragma unroll
    for (int mt = 0; mt < 4; ++mt)
      af[mt] = *reinterpret_cast<short8*>(&as_[(wr * 64 + mt * 16 + l16) * 40 + g * 8]);
#pragma unroll
    for (int nt = 0; nt < 4; ++nt)
      bfr[nt] = *reinterpret_cast<short8*>(&bt[(wc * 64 + nt * 16 + l16) * 40 + g * 8]);
#pragma unroll
    for (int mt = 0; mt < 4; ++mt)
#pragma unroll
      for (int nt = 0; nt < 4; ++nt)
        acc[mt][nt] = __builtin_amdgcn_mfma_f32_16x16x32_bf16(af[mt], bfr[nt], acc[mt][nt], 0, 0, 0);
    __syncthreads();
  }
#pragma unroll
  for (int nt = 0; nt < 4; ++nt) {
    int col = c0 + wc * 64 + nt * 16 + l16;
    float pb = proj_b[col];
#pragma unroll
    for (int mt = 0; mt < 4; ++mt)
#pragma unroll
      for (int j = 0; j < 4; ++j) {
        int row = m0 + wr * 64 + mt * 16 + g * 4 + j;
        out[(size_t)row * 512 + col] = acc[mt][nt][j] + pb;
      }
  }
}

extern "C" void kernel_launch(void* const* d_in, const int* in_sizes, int n_in,
                              void* d_out, int out_size, void* d_ws, size_t ws_size,
                              hipStream_t stream) {
  const float* x      = (const float*)d_in[0];
  const float* temb   = (const float*)d_in[1];
  const float* qkv_w  = (const float*)d_in[2];
  const float* qkv_b  = (const float*)d_in[3];
  const float* temb_w = (const float*)d_in[4];
  const float* temb_b = (const float*)d_in[5];
  const float* rpb    = (const float*)d_in[6];
  const float* proj_w = (const float*)d_in[7];
  const float* proj_b = (const float*)d_in[8];
  // d_in[9] rp_index: unused — index is computed analytically in-kernel.
  float* out = (float*)d_out;

  char* ws = (char*)d_ws;
  float* tm = (float*)ws;                                    // 256*1536*4 = 1.5 MB
  unsigned short* attn = (unsigned short*)(ws + (size_t)B_ * 1536 * 4);  // 64 MB bf16

  temb_mod_kernel<<<B_, 256, 0, stream>>>(temb, temb_w, temb_b, qkv_b, tm);
  fused_attn_kernel<<<B_ * H_, 512, 0, stream>>>(x, qkv_w, rpb, tm, attn);
  proj_kernel<<<(B_ * N_ / 128) * (C_ / 128), 256, 0, stream>>>(attn, proj_w, proj_b, out);
}

// Round 2
// 501.587 us; speedup vs baseline: 1.7177x; 1.7177x over previous
//
#include <hip/hip_runtime.h>
#include <hip/hip_bf16.h>

#define B_ 256
#define N_ 256
#define H_ 16
#define SCALE_ 0.17677669529663687f

typedef __attribute__((ext_vector_type(8))) short short8;
typedef __attribute__((ext_vector_type(4))) float f32x4v;
typedef unsigned int u32;

// async global->LDS, 16B per lane. LDS dest must be wave-uniform base (+lane*16).
#define GLOAD16(gptr, lptr)                                                        \
  __builtin_amdgcn_global_load_lds((const __attribute__((address_space(1))) u32*)(gptr), \
                                   (__attribute__((address_space(3))) u32*)(lptr), 16, 0, 0)

static __device__ __forceinline__ unsigned short f2bf(float f) {
  union { float f; unsigned u; } x; x.f = f;
  unsigned r = x.u + 0x7fffu + ((x.u >> 16) & 1u);
  return (unsigned short)(r >> 16);
}
static __device__ __forceinline__ float bf2f(unsigned short s) {
  union { unsigned u; float f; } x; x.u = ((unsigned)s) << 16;
  return x.f;
}

// ---- converters ----
__global__ void cvt_x_kernel(const float* __restrict__ in, unsigned short* __restrict__ out, int n8) {
  int i = blockIdx.x * 256 + threadIdx.x;
  int stride = gridDim.x * 256;
  for (; i < n8; i += stride) {
    const float4* p = reinterpret_cast<const float4*>(in + (size_t)i * 8);
    float4 a = p[0], b = p[1];
    ushort4 r0 = make_ushort4(f2bf(a.x), f2bf(a.y), f2bf(a.z), f2bf(a.w));
    ushort4 r1 = make_ushort4(f2bf(b.x), f2bf(b.y), f2bf(b.z), f2bf(b.w));
    ushort4* q = reinterpret_cast<ushort4*>(out + (size_t)i * 8);
    q[0] = r0; q[1] = r1;
  }
}

// transpose+convert W [512][ncols] f32 -> WT [ncols][512] bf16
__global__ void cvt_wT_kernel(const float* __restrict__ in, unsigned short* __restrict__ out, int ncols) {
  __shared__ float tile[32][65];
  const int nb = ncols >> 6;
  const int k0 = (blockIdx.x / nb) << 5;
  const int n0 = (blockIdx.x % nb) << 6;
  const int t = threadIdx.x;
  {
    int kk = t >> 3, c0 = (t & 7) << 3;
    const float* src = in + (size_t)(k0 + kk) * ncols + n0 + c0;
    float4 v0 = *reinterpret_cast<const float4*>(src);
    float4 v1 = *reinterpret_cast<const float4*>(src + 4);
    tile[kk][c0 + 0] = v0.x; tile[kk][c0 + 1] = v0.y; tile[kk][c0 + 2] = v0.z; tile[kk][c0 + 3] = v0.w;
    tile[kk][c0 + 4] = v1.x; tile[kk][c0 + 5] = v1.y; tile[kk][c0 + 6] = v1.z; tile[kk][c0 + 7] = v1.w;
  }
  __syncthreads();
  {
    int nn = t >> 2, c0 = (t & 3) << 3;
    unsigned short* dst = out + (size_t)(n0 + nn) * 512 + k0 + c0;
    ushort4 a = make_ushort4(f2bf(tile[c0 + 0][nn]), f2bf(tile[c0 + 1][nn]),
                             f2bf(tile[c0 + 2][nn]), f2bf(tile[c0 + 3][nn]));
    ushort4 b = make_ushort4(f2bf(tile[c0 + 4][nn]), f2bf(tile[c0 + 5][nn]),
                             f2bf(tile[c0 + 6][nn]), f2bf(tile[c0 + 7][nn]));
    *reinterpret_cast<ushort4*>(dst) = a;
    *reinterpret_cast<ushort4*>(dst + 4) = b;
  }
}

// K0: tm[b][j] = temb[b]@temb_w[:,j] + temb_b[j] + qkv_b[j]; 4 b per block
__global__ void temb_mod_kernel(const float* __restrict__ temb,
                                const float* __restrict__ temb_w,
                                const float* __restrict__ temb_b,
                                const float* __restrict__ qkv_b,
                                float* __restrict__ tm) {
  __shared__ float ts[4][512];
  const int b0 = blockIdx.x << 2, t = threadIdx.x;
  for (int i = t; i < 2048; i += 256) ts[i >> 9][i & 511] = temb[(size_t)b0 * 512 + i];
  __syncthreads();
  float acc[4][6];
#pragma unroll
  for (int u = 0; u < 6; ++u) {
    float bsum = temb_b[t + u * 256] + qkv_b[t + u * 256];
#pragma unroll
    for (int bb = 0; bb < 4; ++bb) acc[bb][u] = bsum;
  }
  for (int k = 0; k < 512; ++k) {
    float t0 = ts[0][k], t1 = ts[1][k], t2 = ts[2][k], t3 = ts[3][k];
#pragma unroll
    for (int u = 0; u < 6; ++u) {
      float wv = temb_w[(size_t)k * 1536 + t + u * 256];
      acc[0][u] += t0 * wv; acc[1][u] += t1 * wv; acc[2][u] += t2 * wv; acc[3][u] += t3 * wv;
    }
  }
#pragma unroll
  for (int bb = 0; bb < 4; ++bb)
#pragma unroll
    for (int u = 0; u < 6; ++u) tm[(size_t)(b0 + bb) * 1536 + t + u * 256] = acc[bb][u];
}

// K1: fused qkv-GEMM (gload_lds staged) + single-pass flash attention per (b,h)
__global__ __launch_bounds__(512, 4)
void fused_attn_kernel(const unsigned short* __restrict__ xb16,   // [65536][512]
                       const unsigned short* __restrict__ wT,     // [1536][512]
                       const float* __restrict__ rpb,
                       const float* __restrict__ tm,
                       unsigned short* __restrict__ attn_out) {
  // LDS map (bytes), total 80384:
  //  [0,16384)      xs [256][32]     (phase A)   | flash: biasT f32 [961] at [0,3844)
  //  [16384,22528)  wTs [96][32]     (phase A)
  //  [22528,43008)  qs [256][40]     -> per-wave pbuf [32][40] after aq load
  //  [43008,63488)  ks [256][40]
  //  [63488,80384)  vTs [32][264]
  __shared__ char smem[80384];
  short* xs  = (short*)smem;
  short* wTs = (short*)(smem + 16384);
  float* biasT = (float*)smem;
  short* qs  = (short*)(smem + 22528);
  short* ks  = (short*)(smem + 43008);
  short* vTs = (short*)(smem + 63488);

  const int bh = blockIdx.x;
  const int b = bh >> 4, h = bh & 15;
  const int tid = threadIdx.x;
  const int w = tid >> 6, l = tid & 63;
  const int l16 = l & 15, g = l >> 4;
  const int lrow = l >> 2, lcol = (l & 3) << 3;

  // gload sources (per-lane global addr, wave-uniform LDS base)
  const unsigned short* xsrc0 = xb16 + (size_t)(b * 256 + w * 16 + lrow) * 512 + lcol;
  const unsigned short* xsrc1 = xsrc0 + (size_t)128 * 512;
  const int row96 = w * 16 + lrow;
  const int wpart = row96 >> 5, wsub = row96 & 31;
  const unsigned short* wsrc = wT + (size_t)(wpart * 512 + h * 32 + wsub) * 512 + lcol;
  short* ldsA0 = xs + (size_t)w * 512;
  short* ldsA1 = xs + (size_t)(8 + w) * 512;
  short* ldsW  = wTs + (size_t)w * 512;

  f32x4v acc[2][6];
#pragma unroll
  for (int mt = 0; mt < 2; ++mt)
#pragma unroll
    for (int nt = 0; nt < 6; ++nt) acc[mt][nt] = (f32x4v)(0.0f);

  // ---- Phase A: qkv tile = x[b] @ wT(96 rows of head h) ----
  for (int k0 = 0; k0 < 512; k0 += 32) {
    GLOAD16(xsrc0 + k0, ldsA0);
    GLOAD16(xsrc1 + k0, ldsA1);
    if (w < 6) GLOAD16(wsrc + k0, ldsW);
    __syncthreads();
    short8 af[2], bfr[6];
#pragma unroll
    for (int mt = 0; mt < 2; ++mt)
      af[mt] = *reinterpret_cast<short8*>(&xs[(w * 32 + mt * 16 + l16) * 32 + g * 8]);
#pragma unroll
    for (int nt = 0; nt < 6; ++nt)
      bfr[nt] = *reinterpret_cast<short8*>(&wTs[(nt * 16 + l16) * 32 + g * 8]);
#pragma unroll
    for (int mt = 0; mt < 2; ++mt)
#pragma unroll
      for (int nt = 0; nt < 6; ++nt)
        acc[mt][nt] = __builtin_amdgcn_mfma_f32_16x16x32_bf16(af[mt], bfr[nt], acc[mt][nt], 0, 0, 0);
    __syncthreads();
  }

  // ---- epilogue A: + tm bias, scale q, scatter q/k/vT ----
  const float* tmb = tm + (size_t)b * 1536;
#pragma unroll
  for (int nt = 0; nt < 6; ++nt) {
    const int prt = nt >> 1;                 // 0=q 1=k 2=v (tile cols grouped 32)
    const int d = ((nt & 1) << 4) + l16;     // 0..31 within part
    const float tmv = tmb[(prt << 9) + (h << 5) + d];
#pragma unroll
    for (int mt = 0; mt < 2; ++mt) {
      const int r0 = w * 32 + mt * 16 + g * 4;
      if (prt == 2) {
        ushort4 pk;
        pk.x = f2bf(acc[mt][nt][0] + tmv);
        pk.y = f2bf(acc[mt][nt][1] + tmv);
        pk.z = f2bf(acc[mt][nt][2] + tmv);
        pk.w = f2bf(acc[mt][nt][3] + tmv);
        *reinterpret_cast<ushort4*>(&vTs[d * 264 + r0]) = pk;
      } else if (prt == 0) {
#pragma unroll
        for (int j = 0; j < 4; ++j)
          qs[(r0 + j) * 40 + d] = (short)f2bf((acc[mt][nt][j] + tmv) * SCALE_);
      } else {
#pragma unroll
        for (int j = 0; j < 4; ++j)
          ks[(r0 + j) * 40 + d] = (short)f2bf(acc[mt][nt][j] + tmv);
      }
    }
  }
  // stage bias into (now dead) region0
  for (int e = tid; e < 961; e += 512) biasT[e] = rpb[e * 16 + h];
  __syncthreads();

  // ---- flash attention, zero barriers ----
  short8 aq[2];
#pragma unroll
  for (int mt = 0; mt < 2; ++mt)
    aq[mt] = *reinterpret_cast<short8*>(&qs[(w * 32 + mt * 16 + l16) * 40 + g * 8]);
  short* pw = qs + w * (32 * 40);   // per-wave P buffer aliases own q rows (now dead)

  float mrun[2][4], lsum[2][4];
  f32x4v oacc[2][2];
#pragma unroll
  for (int mt = 0; mt < 2; ++mt) {
#pragma unroll
    for (int j = 0; j < 4; ++j) { mrun[mt][j] = -1.0e30f; lsum[mt][j] = 0.0f; }
#pragma unroll
    for (int nt = 0; nt < 2; ++nt) oacc[mt][nt] = (f32x4v)(0.0f);
  }

  for (int kc = 0; kc < 8; ++kc) {
    float sv[2][2][4];
#pragma unroll
    for (int ct = 0; ct < 2; ++ct) {
      const int kt = kc * 2 + ct;
      short8 bk = *reinterpret_cast<short8*>(&ks[(kt * 16 + l16) * 40 + g * 8]);
      const int ck = kt * 16 + l16;
      const int cky = ck >> 4, ckx = ck & 15;
#pragma unroll
      for (int mt = 0; mt < 2; ++mt) {
        f32x4v s4 = __builtin_amdgcn_mfma_f32_16x16x32_bf16(aq[mt], bk, (f32x4v)(0.0f), 0, 0, 0);
#pragma unroll
        for (int j = 0; j < 4; ++j) {
          const int rq = w * 32 + mt * 16 + g * 4 + j;
          sv[mt][ct][j] = s4[j] + biasT[((rq >> 4) - cky + 15) * 31 + ((rq & 15) - ckx + 15)];
        }
      }
    }
#pragma unroll
    for (int mt = 0; mt < 2; ++mt)
#pragma unroll
      for (int j = 0; j < 4; ++j) {
        float cm = fmaxf(sv[mt][0][j], sv[mt][1][j]);
        cm = fmaxf(cm, __shfl_xor(cm, 1));
        cm = fmaxf(cm, __shfl_xor(cm, 2));
        cm = fmaxf(cm, __shfl_xor(cm, 4));
        cm = fmaxf(cm, __shfl_xor(cm, 8));
        const float mo = mrun[mt][j];
        const float mn = fmaxf(mo, cm);
        const float r = __expf(mo - mn);
        mrun[mt][j] = mn;
        lsum[mt][j] *= r;
        oacc[mt][0][j] *= r;
        oacc[mt][1][j] *= r;
        const float p0 = __expf(sv[mt][0][j] - mn);
        const float p1 = __expf(sv[mt][1][j] - mn);
        lsum[mt][j] += p0 + p1;
        const int pr = mt * 16 + g * 4 + j;
        pw[pr * 40 + l16] = (short)f2bf(p0);
        pw[pr * 40 + 16 + l16] = (short)f2bf(p1);
      }
#pragma unroll
    for (int mt = 0; mt < 2; ++mt) {
      short8 ap = *reinterpret_cast<short8*>(&pw[(mt * 16 + l16) * 40 + g * 8]);
#pragma unroll
      for (int nt = 0; nt < 2; ++nt) {
        short8 bv = *reinterpret_cast<short8*>(&vTs[(nt * 16 + l16) * 264 + kc * 32 + g * 8]);
        oacc[mt][nt] = __builtin_amdgcn_mfma_f32_16x16x32_bf16(ap, bv, oacc[mt][nt], 0, 0, 0);
      }
    }
  }

  // normalize + write
  unsigned short* ao = attn_out + (size_t)(b * 256) * 512 + h * 32;
#pragma unroll
  for (int mt = 0; mt < 2; ++mt)
#pragma unroll
    for (int j = 0; j < 4; ++j) {
      float s = lsum[mt][j];
      s += __shfl_xor(s, 1); s += __shfl_xor(s, 2);
      s += __shfl_xor(s, 4); s += __shfl_xor(s, 8);
      const float inv = 1.0f / s;
      oacc[mt][0][j] *= inv;
      oacc[mt][1][j] *= inv;
    }
#pragma unroll
  for (int mt = 0; mt < 2; ++mt)
#pragma unroll
    for (int nt = 0; nt < 2; ++nt)
#pragma unroll
      for (int j = 0; j < 4; ++j) {
        const int row = w * 32 + mt * 16 + g * 4 + j;
        ao[(size_t)row * 512 + nt * 16 + l16] = f2bf(oacc[mt][nt][j]);
      }
}

// K2: out = attn @ proj_wT^T + proj_b  (gload_lds, 128x128 tile, 4 waves)
__global__ __launch_bounds__(256)
void proj_kernel(const unsigned short* __restrict__ A,    // [65536][512] bf16
                 const unsigned short* __restrict__ BT,   // [512][512] bf16
                 const float* __restrict__ proj_b,
                 float* __restrict__ out) {
  __shared__ short As[128 * 32];
  __shared__ short Bs[128 * 32];
  const int bid = blockIdx.x;
  const int m0 = (bid & 511) << 7, n0 = (bid >> 9) << 7;
  const int tid = threadIdx.x;
  const int w = tid >> 6, l = tid & 63, l16 = l & 15, g = l >> 4;
  const int wr = w >> 1, wc = w & 1;
  const int lrow = l >> 2, lcol = (l & 3) << 3;

  const unsigned short* asrc0 = A + (size_t)(m0 + w * 16 + lrow) * 512 + lcol;
  const unsigned short* asrc1 = asrc0 + (size_t)64 * 512;
  const unsigned short* bsrc0 = BT + (size_t)(n0 + w * 16 + lrow) * 512 + lcol;
  const unsigned short* bsrc1 = bsrc0 + (size_t)64 * 512;
  short* ldsA0 = As + w * 512; short* ldsA1 = As + (4 + w) * 512;
  short* ldsB0 = Bs + w * 512; short* ldsB1 = Bs + (4 + w) * 512;

  f32x4v acc[4][4];
#pragma unroll
  for (int mt = 0; mt < 4; ++mt)
#pragma unroll
    for (int nt = 0; nt < 4; ++nt) acc[mt][nt] = (f32x4v)(0.0f);

  for (int k0 = 0; k0 < 512; k0 += 32) {
    GLOAD16(asrc0 + k0, ldsA0);
    GLOAD16(asrc1 + k0, ldsA1);
    GLOAD16(bsrc0 + k0, ldsB0);
    GLOAD16(bsrc1 + k0, ldsB1);
    __syncthreads();
    short8 af[4], bfr[4];
#pragma unroll
    for (int mt = 0; mt < 4; ++mt)
      af[mt] = *reinterpret_cast<short8*>(&As[(wr * 64 + mt * 16 + l16) * 32 + g * 8]);
#pragma unroll
    for (int nt = 0; nt < 4; ++nt)
      bfr[nt] = *reinterpret_cast<short8*>(&Bs[(wc * 64 + nt * 16 + l16) * 32 + g * 8]);
#pragma unroll
    for (int mt = 0; mt < 4; ++mt)
#pragma unroll
      for (int nt = 0; nt < 4; ++nt)
        acc[mt][nt] = __builtin_amdgcn_mfma_f32_16x16x32_bf16(af[mt], bfr[nt], acc[mt][nt], 0, 0, 0);
    __syncthreads();
  }
#pragma unroll
  for (int nt = 0; nt < 4; ++nt) {
    const int col = n0 + wc * 64 + nt * 16 + l16;
    const float pb = proj_b[col];
#pragma unroll
    for (int mt = 0; mt < 4; ++mt)
#pragma unroll
      for (int j = 0; j < 4; ++j)
        out[(size_t)(m0 + wr * 64 + mt * 16 + g * 4 + j) * 512 + col] = acc[mt][nt][j] + pb;
  }
}

extern "C" void kernel_launch(void* const* d_in, const int* in_sizes, int n_in,
                              void* d_out, int out_size, void* d_ws, size_t ws_size,
                              hipStream_t stream) {
  const float* x      = (const float*)d_in[0];
  const float* temb   = (const float*)d_in[1];
  const float* qkv_w  = (const float*)d_in[2];
  const float* qkv_b  = (const float*)d_in[3];
  const float* temb_w = (const float*)d_in[4];
  const float* temb_b = (const float*)d_in[5];
  const float* rpb    = (const float*)d_in[6];
  const float* proj_w = (const float*)d_in[7];
  const float* proj_b = (const float*)d_in[8];
  float* out = (float*)d_out;

  char* ws = (char*)d_ws;
  float* tm               = (float*)ws;                                  // 1,572,864 B
  unsigned short* xb16    = (unsigned short*)(ws + 1572864);             // 67,108,864 B
  unsigned short* qkv_wT  = (unsigned short*)(ws + 1572864 + 67108864);  // 1,572,864 B
  unsigned short* proj_wT = (unsigned short*)(ws + 1572864 + 67108864 + 1572864);  // 524,288 B
  unsigned short* attn_ws = (unsigned short*)(ws + 1572864 + 67108864 + 1572864 + 524288); // 67,108,864 B

  cvt_x_kernel<<<2048, 256, 0, stream>>>(x, xb16, (256 * 256 * 512) / 8);
  cvt_wT_kernel<<<16 * 24, 256, 0, stream>>>(qkv_w, qkv_wT, 1536);
  cvt_wT_kernel<<<16 * 8, 256, 0, stream>>>(proj_w, proj_wT, 512);
  temb_mod_kernel<<<64, 256, 0, stream>>>(temb, temb_w, temb_b, qkv_b, tm);
  fused_attn_kernel<<<B_ * H_, 512, 0, stream>>>(xb16, qkv_wT, rpb, tm, attn_ws);
  proj_kernel<<<512 * 4, 256, 0, stream>>>(attn_ws, proj_wT, proj_b, out);
}